// Round 2
// baseline (340.252 us; speedup 1.0000x reference)
//
#include <hip/hip_runtime.h>
#include <hip/hip_bf16.h>

// CoverTreeLoss: aw[j] = W[j] + sum(W[ancestors(j)]); logits = x @ aw^T;
// loss = mean(logsumexp(logits[b]) - logits[b, y[b]]).
// B=4096, H=512, T=10000 (pad to 10112 = 79*128), C=16384.
// R2: register staging (ushort8 -> ds_write_b128) instead of global_load_lds
// to bisect the R1 device abort.

typedef __bf16 bf16x8 __attribute__((ext_vector_type(8)));
typedef float f32x4 __attribute__((ext_vector_type(4)));
typedef unsigned short u16x8 __attribute__((ext_vector_type(8)));

#define BATCH 4096
#define HID 512
#define TCLS 10000
#define NPAD 10112   // 79 * 128

__device__ __forceinline__ unsigned short f2bf(float f) {
    unsigned u = __float_as_uint(f);
    unsigned r = (u + 0x7fffu + ((u >> 16) & 1u)) >> 16;  // RNE, finite inputs only
    return (unsigned short)r;
}

// ---------------- kernel 1: x fp32 -> bf16 ----------------
__global__ __launch_bounds__(256) void cvt_x_kernel(const float* __restrict__ x,
                                                    unsigned short* __restrict__ xb, int n) {
    int i = (blockIdx.x * 256 + threadIdx.x) * 4;
    if (i < n) {
        float4 v = *(const float4*)(x + i);
        ushort4 o;
        o.x = f2bf(v.x); o.y = f2bf(v.y); o.z = f2bf(v.z); o.w = f2bf(v.w);
        *(ushort4*)(xb + i) = o;
    }
}

// ---------------- kernel 2: added_weights (bf16, zero-padded rows) ----------------
// one block per class row; segment_id is sorted ascending -> binary search [start,end)
__global__ __launch_bounds__(256) void build_aw_kernel(const float* __restrict__ W,
                                                       const int* __restrict__ anc,
                                                       const int* __restrict__ seg,
                                                       int nnz,
                                                       unsigned short* __restrict__ awb) {
    int j = blockIdx.x;
    int h = threadIdx.x * 2;
    unsigned short* dst = awb + (size_t)j * HID + h;
    if (j >= TCLS) {  // padding rows must be zero (GEMM has no guards)
        *(ushort2*)dst = make_ushort2(0, 0);
        return;
    }
    int lo = 0, hi = nnz;
    while (lo < hi) { int mid = (lo + hi) >> 1; if (seg[mid] < j) lo = mid + 1; else hi = mid; }
    int start = lo;
    hi = nnz;
    while (lo < hi) { int mid = (lo + hi) >> 1; if (seg[mid] <= j) lo = mid + 1; else hi = mid; }
    int end = lo;
    float2 a = *(const float2*)(W + (size_t)j * HID + h);
    for (int k = start; k < end; k++) {
        float2 w = *(const float2*)(W + (size_t)anc[k] * HID + h);
        a.x += w.x; a.y += w.y;
    }
    ushort2 o; o.x = f2bf(a.x); o.y = f2bf(a.y);
    *(ushort2*)dst = o;
}

// ---------------- kernel 3: GEMM  C[M,T] = A[M,K] * B[NPAD,K]^T ----------------
#define BM 128
#define BN 128
#define BK 32
__global__ __launch_bounds__(256) void gemm_bt_kernel(const unsigned short* __restrict__ A,
                                                      const unsigned short* __restrict__ B,
                                                      float* __restrict__ C) {
    __shared__ __align__(16) unsigned short lds_a[BM * BK];
    __shared__ __align__(16) unsigned short lds_b[BN * BK];

    const int tid = threadIdx.x;
    const int bm = blockIdx.y * BM;
    const int bn = blockIdx.x * BN;
    const int wave = tid >> 6;
    const int lane = tid & 63;
    const int l15 = lane & 15;
    const int quad = lane >> 4;
    const int wm = (wave >> 1) * 64;
    const int wn = (wave & 1) * 64;

    f32x4 acc[4][4];
#pragma unroll
    for (int i = 0; i < 4; i++)
#pragma unroll
        for (int j = 0; j < 4; j++) acc[i][j] = (f32x4)0.f;

    // staging: 512 chunks of 16B per tile; thread does chunks {tid, tid+256}.
    // chunk c -> row c>>2, 16B-segment c&3.
    const int c0 = tid, c1 = tid + 256;
    const unsigned short* a_g0 = A + (size_t)(bm + (c0 >> 2)) * HID + (c0 & 3) * 8;
    const unsigned short* a_g1 = A + (size_t)(bm + (c1 >> 2)) * HID + (c1 & 3) * 8;
    const unsigned short* b_g0 = B + (size_t)(bn + (c0 >> 2)) * HID + (c0 & 3) * 8;
    const unsigned short* b_g1 = B + (size_t)(bn + (c1 >> 2)) * HID + (c1 & 3) * 8;
    unsigned short* a_l0 = &lds_a[c0 * 8];
    unsigned short* a_l1 = &lds_a[c1 * 8];
    unsigned short* b_l0 = &lds_b[c0 * 8];
    unsigned short* b_l1 = &lds_b[c1 * 8];

    for (int k0 = 0; k0 < HID; k0 += BK) {
        u16x8 ra0 = *(const u16x8*)(a_g0 + k0);
        u16x8 ra1 = *(const u16x8*)(a_g1 + k0);
        u16x8 rb0 = *(const u16x8*)(b_g0 + k0);
        u16x8 rb1 = *(const u16x8*)(b_g1 + k0);
        *(u16x8*)a_l0 = ra0;
        *(u16x8*)a_l1 = ra1;
        *(u16x8*)b_l0 = rb0;
        *(u16x8*)b_l1 = rb1;
        __syncthreads();  // staged tile visible

        bf16x8 af[4], bfr[4];
#pragma unroll
        for (int mt = 0; mt < 4; mt++)
            af[mt] = *(const bf16x8*)&lds_a[(wm + mt * 16 + l15) * BK + quad * 8];
#pragma unroll
        for (int nt = 0; nt < 4; nt++)
            bfr[nt] = *(const bf16x8*)&lds_b[(wn + nt * 16 + l15) * BK + quad * 8];
#pragma unroll
        for (int mt = 0; mt < 4; mt++)
#pragma unroll
            for (int nt = 0; nt < 4; nt++)
                acc[mt][nt] = __builtin_amdgcn_mfma_f32_16x16x32_bf16(af[mt], bfr[nt],
                                                                      acc[mt][nt], 0, 0, 0);
        __syncthreads();  // compute done before next stage overwrites
    }

    // epilogue: C/D layout col=lane&15, row=quad*4+reg  [verified m89/m91]
#pragma unroll
    for (int nt = 0; nt < 4; nt++) {
        int col = bn + wn + nt * 16 + l15;
        if (col < TCLS) {
#pragma unroll
            for (int mt = 0; mt < 4; mt++) {
                int row = bm + wm + mt * 16 + quad * 4;
#pragma unroll
                for (int r = 0; r < 4; r++)
                    C[(size_t)(row + r) * TCLS + col] = acc[mt][nt][r];
            }
        }
    }
}

// ---------------- kernel 4: per-row logsumexp + pick -> loss term ----------------
__global__ __launch_bounds__(256) void softmax_loss_kernel(const float* __restrict__ logits,
                                                           const int* __restrict__ y,
                                                           float* __restrict__ terms) {
    int row = blockIdx.x;
    const float* rp = logits + (size_t)row * TCLS;
    float m = -INFINITY, s = 0.f;
    for (int c = threadIdx.x; c < TCLS; c += 256) {
        float v = rp[c];
        float nm = fmaxf(m, v);
        s = s * __expf(m - nm) + __expf(v - nm);
        m = nm;
    }
#pragma unroll
    for (int off = 32; off > 0; off >>= 1) {
        float om = __shfl_down(m, off, 64);
        float os = __shfl_down(s, off, 64);
        float nm = fmaxf(m, om);
        s = s * __expf(m - nm) + os * __expf(om - nm);
        m = nm;
    }
    __shared__ float sm[4], ss[4];
    int w = threadIdx.x >> 6;
    if ((threadIdx.x & 63) == 0) { sm[w] = m; ss[w] = s; }
    __syncthreads();
    if (threadIdx.x == 0) {
        m = sm[0]; s = ss[0];
        for (int i = 1; i < 4; i++) {
            float nm = fmaxf(m, sm[i]);
            s = s * __expf(m - nm) + ss[i] * __expf(sm[i] - nm);
            m = nm;
        }
        terms[row] = m + __logf(s) - rp[y[row]];
    }
}

// ---------------- kernel 5: mean of terms -> d_out[0] ----------------
__global__ __launch_bounds__(256) void reduce_loss_kernel(const float* __restrict__ terms,
                                                          float* __restrict__ out) {
    float s = 0.f;
    for (int i = threadIdx.x; i < BATCH; i += 256) s += terms[i];
#pragma unroll
    for (int off = 32; off > 0; off >>= 1) s += __shfl_down(s, off, 64);
    __shared__ float sh[4];
    if ((threadIdx.x & 63) == 0) sh[threadIdx.x >> 6] = s;
    __syncthreads();
    if (threadIdx.x == 0) out[0] = (sh[0] + sh[1] + sh[2] + sh[3]) * (1.0f / BATCH);
}

extern "C" void kernel_launch(void* const* d_in, const int* in_sizes, int n_in,
                              void* d_out, int out_size, void* d_ws, size_t ws_size,
                              hipStream_t stream) {
    const float* x = (const float*)d_in[0];
    const int* y = (const int*)d_in[1];
    const float* W = (const float*)d_in[2];
    const int* anc = (const int*)d_in[3];
    const int* seg = (const int*)d_in[4];
    int nnz = in_sizes[3];

    unsigned short* xb = (unsigned short*)d_ws;               // BATCH*HID bf16
    unsigned short* awb = xb + (size_t)BATCH * HID;           // NPAD*HID bf16
    float* terms = (float*)(awb + (size_t)NPAD * HID);        // BATCH fp32
    float* loss = (float*)d_out;
    float* logits = loss + 1;                                 // [BATCH, TCLS]

    cvt_x_kernel<<<(BATCH * HID) / (256 * 4), 256, 0, stream>>>(x, xb, BATCH * HID);
    build_aw_kernel<<<NPAD, 256, 0, stream>>>(W, anc, seg, nnz, awb);
    dim3 grid(NPAD / BN, BATCH / BM);
    gemm_bt_kernel<<<grid, 256, 0, stream>>>(xb, awb, logits);
    softmax_loss_kernel<<<BATCH, 256, 0, stream>>>(logits, y, terms);
    reduce_loss_kernel<<<1, 256, 0, stream>>>(terms, loss);
}

// Round 3
// 335.717 us; speedup vs baseline: 1.0135x; 1.0135x over previous
//
#include <hip/hip_runtime.h>
#include <hip/hip_bf16.h>

// CoverTreeLoss: aw[j] = W[j] + sum(W[ancestors(j)]); logits = x @ aw^T;
// loss = mean(logsumexp(logits[b]) - logits[b, y[b]]).
// B=4096, H=512, T=10000 (pad to 10112 = 79*128), C=16384.
// R3: LDS-transposed contiguous epilogue (logits base is d_out+1 -> only
// 4B-aligned -> scalar-but-dense stores), fused per-block softmax partials
// (kills the 164MB logits re-read), register-prefetch double buffering.

typedef __bf16 bf16x8 __attribute__((ext_vector_type(8)));
typedef float f32x4 __attribute__((ext_vector_type(4)));
typedef unsigned short u16x8 __attribute__((ext_vector_type(8)));

#define BATCH 4096
#define HID 512
#define TCLS 10000
#define NPAD 10112   // 79 * 128
#define NBLK 79      // col-blocks = partials per row

__device__ __forceinline__ unsigned short f2bf(float f) {
    unsigned u = __float_as_uint(f);
    unsigned r = (u + 0x7fffu + ((u >> 16) & 1u)) >> 16;  // RNE, finite inputs only
    return (unsigned short)r;
}

// ---------------- kernel 1: x fp32 -> bf16 ----------------
__global__ __launch_bounds__(256) void cvt_x_kernel(const float* __restrict__ x,
                                                    unsigned short* __restrict__ xb, int n) {
    int i = (blockIdx.x * 256 + threadIdx.x) * 4;
    if (i < n) {
        float4 v = *(const float4*)(x + i);
        ushort4 o;
        o.x = f2bf(v.x); o.y = f2bf(v.y); o.z = f2bf(v.z); o.w = f2bf(v.w);
        *(ushort4*)(xb + i) = o;
    }
}

// ---------------- kernel 2: added_weights (bf16, zero-padded rows) ----------------
__global__ __launch_bounds__(256) void build_aw_kernel(const float* __restrict__ W,
                                                       const int* __restrict__ anc,
                                                       const int* __restrict__ seg,
                                                       int nnz,
                                                       unsigned short* __restrict__ awb) {
    int j = blockIdx.x;
    int h = threadIdx.x * 2;
    unsigned short* dst = awb + (size_t)j * HID + h;
    if (j >= TCLS) {  // padding rows must be zero (GEMM has no guards)
        *(ushort2*)dst = make_ushort2(0, 0);
        return;
    }
    int lo = 0, hi = nnz;
    while (lo < hi) { int mid = (lo + hi) >> 1; if (seg[mid] < j) lo = mid + 1; else hi = mid; }
    int start = lo;
    hi = nnz;
    while (lo < hi) { int mid = (lo + hi) >> 1; if (seg[mid] <= j) lo = mid + 1; else hi = mid; }
    int end = lo;
    float2 a = *(const float2*)(W + (size_t)j * HID + h);
    for (int k = start; k < end; k++) {
        float2 w = *(const float2*)(W + (size_t)anc[k] * HID + h);
        a.x += w.x; a.y += w.y;
    }
    ushort2 o; o.x = f2bf(a.x); o.y = f2bf(a.y);
    *(ushort2*)dst = o;
}

// ---------------- kernel 3: GEMM + fused softmax partials ----------------
#define BM 128
#define BN 128
#define BK 32
__global__ __launch_bounds__(256) void gemm_fused_kernel(const unsigned short* __restrict__ A,
                                                         const unsigned short* __restrict__ B,
                                                         float* __restrict__ C,
                                                         float2* __restrict__ partials) {
    // smem serves 3 phases: (a) staging 2x4096 shorts = 16384B,
    // (b) per-row partial merge 128*2 float2 = 2048B, (c) C transpose 32*132 floats = 16896B
    __shared__ __align__(16) unsigned char smem[32 * 132 * 4];
    unsigned short* lds_a = (unsigned short*)smem;
    unsigned short* lds_b = ((unsigned short*)smem) + BM * BK;
    float* ldsc = (float*)smem;
    float2* pm = (float2*)smem;

    const int tid = threadIdx.x;
    const int bm = blockIdx.y * BM;
    const int bn = blockIdx.x * BN;
    const int wave = tid >> 6;
    const int lane = tid & 63;
    const int l15 = lane & 15;
    const int quad = lane >> 4;
    const int wm = (wave >> 1) * 64;
    const int wn = (wave & 1) * 64;

    f32x4 acc[4][4];
#pragma unroll
    for (int i = 0; i < 4; i++)
#pragma unroll
        for (int j = 0; j < 4; j++) acc[i][j] = (f32x4)0.f;

    const int c0 = tid, c1 = tid + 256;
    const unsigned short* a_g0 = A + (size_t)(bm + (c0 >> 2)) * HID + (c0 & 3) * 8;
    const unsigned short* a_g1 = A + (size_t)(bm + (c1 >> 2)) * HID + (c1 & 3) * 8;
    const unsigned short* b_g0 = B + (size_t)(bn + (c0 >> 2)) * HID + (c0 & 3) * 8;
    const unsigned short* b_g1 = B + (size_t)(bn + (c1 >> 2)) * HID + (c1 & 3) * 8;
    unsigned short* a_l0 = &lds_a[c0 * 8];
    unsigned short* a_l1 = &lds_a[c1 * 8];
    unsigned short* b_l0 = &lds_b[c0 * 8];
    unsigned short* b_l1 = &lds_b[c1 * 8];

    // prefetch k=0 tile into registers
    u16x8 ra0 = *(const u16x8*)a_g0;
    u16x8 ra1 = *(const u16x8*)a_g1;
    u16x8 rb0 = *(const u16x8*)b_g0;
    u16x8 rb1 = *(const u16x8*)b_g1;

    for (int k0 = 0; k0 < HID; k0 += BK) {
        *(u16x8*)a_l0 = ra0;
        *(u16x8*)a_l1 = ra1;
        *(u16x8*)b_l0 = rb0;
        *(u16x8*)b_l1 = rb1;
        __syncthreads();

        int kn = k0 + BK;
        if (kn < HID) {  // prefetch next tile; overlaps with MFMA below
            ra0 = *(const u16x8*)(a_g0 + kn);
            ra1 = *(const u16x8*)(a_g1 + kn);
            rb0 = *(const u16x8*)(b_g0 + kn);
            rb1 = *(const u16x8*)(b_g1 + kn);
        }

        bf16x8 af[4], bfr[4];
#pragma unroll
        for (int mt = 0; mt < 4; mt++)
            af[mt] = *(const bf16x8*)&lds_a[(wm + mt * 16 + l15) * BK + quad * 8];
#pragma unroll
        for (int nt = 0; nt < 4; nt++)
            bfr[nt] = *(const bf16x8*)&lds_b[(wn + nt * 16 + l15) * BK + quad * 8];
#pragma unroll
        for (int mt = 0; mt < 4; mt++)
#pragma unroll
            for (int nt = 0; nt < 4; nt++)
                acc[mt][nt] = __builtin_amdgcn_mfma_f32_16x16x32_bf16(af[mt], bfr[nt],
                                                                      acc[mt][nt], 0, 0, 0);
        __syncthreads();
    }

    // ---- fused softmax partials: per-wave (m,s) over its 64 cols, per row ----
    // C/D layout: col=lane&15, row=quad*4+reg [m89/m91]. Padded cols masked to
    // -1e30 (exp underflows to exact 0 -> no NaN paths anywhere).
    const int colbase = bn + wn + l15;
#pragma unroll
    for (int mt = 0; mt < 4; mt++) {
#pragma unroll
        for (int r = 0; r < 4; r++) {
            float v[4];
#pragma unroll
            for (int nt = 0; nt < 4; nt++)
                v[nt] = (colbase + nt * 16 < TCLS) ? acc[mt][nt][r] : -1e30f;
            float m = fmaxf(fmaxf(v[0], v[1]), fmaxf(v[2], v[3]));
#pragma unroll
            for (int off = 1; off < 16; off <<= 1)
                m = fmaxf(m, __shfl_xor(m, off, 64));
            float s = __expf(v[0] - m) + __expf(v[1] - m) +
                      __expf(v[2] - m) + __expf(v[3] - m);
#pragma unroll
            for (int off = 1; off < 16; off <<= 1)
                s += __shfl_xor(s, off, 64);
            if (l15 == 0) {
                int rowl = wm + mt * 16 + quad * 4 + r;
                pm[rowl * 2 + (wave & 1)] = make_float2(m, s);
            }
        }
    }
    __syncthreads();
    if (tid < 128) {  // merge the two col-halves, write one partial per row
        float2 p0 = pm[tid * 2 + 0];
        float2 p1 = pm[tid * 2 + 1];
        float nm = fmaxf(p0.x, p1.x);
        float s = p0.y * __expf(p0.x - nm) + p1.y * __expf(p1.x - nm);
        partials[(size_t)(bm + tid) * NBLK + blockIdx.x] = make_float2(nm, s);
    }
    __syncthreads();

    // ---- C write via LDS transpose; 4 rounds of 32 rows x 128 cols ----
    // logits base (d_out+1) is only 4B-aligned -> scalar stores, but each
    // instruction covers 256B contiguous per wave (full-line coverage, no RMW).
#pragma unroll
    for (int t = 0; t < 4; t++) {
        if ((wave >> 1) == (t >> 1)) {
            int mtbase = (t & 1) * 2;
#pragma unroll
            for (int mi = 0; mi < 2; mi++) {
                int mt = mtbase + mi;
                int rowl = mi * 16 + quad * 4;
#pragma unroll
                for (int nt = 0; nt < 4; nt++)
#pragma unroll
                    for (int r = 0; r < 4; r++)
                        ldsc[(rowl + r) * 132 + wn + nt * 16 + l15] = acc[mt][nt][r];
            }
        }
        __syncthreads();
#pragma unroll
        for (int e = 0; e < 16; e++) {
            int idx = e * 256 + tid;          // 0..4095
            int rowl = idx >> 7;              // 0..31
            int col = idx & 127;
            int gc = bn + col;
            if (gc < TCLS)
                C[(size_t)(bm + t * 32 + rowl) * TCLS + gc] = ldsc[rowl * 132 + col];
        }
        __syncthreads();
    }
}

// ---------------- kernel 4: lse from partials + gather -> loss terms ----------------
__global__ __launch_bounds__(256) void lse_kernel(const float2* __restrict__ partials,
                                                  const float* __restrict__ logits,
                                                  const int* __restrict__ y,
                                                  float* __restrict__ terms) {
    int row = blockIdx.x * 4 + (threadIdx.x >> 6);
    int lane = threadIdx.x & 63;
    float m = -1e30f, s = 0.f;
    if (lane < NBLK) {
        float2 p = partials[(size_t)row * NBLK + lane];
        m = p.x; s = p.y;
    }
    if (lane + 64 < NBLK) {
        float2 p = partials[(size_t)row * NBLK + lane + 64];
        float nm = fmaxf(m, p.x);
        s = s * __expf(m - nm) + p.y * __expf(p.x - nm);
        m = nm;
    }
#pragma unroll
    for (int off = 1; off < 64; off <<= 1) {
        float om = __shfl_xor(m, off, 64);
        float os = __shfl_xor(s, off, 64);
        float nm = fmaxf(m, om);
        s = s * __expf(m - nm) + os * __expf(om - nm);
        m = nm;
    }
    if (lane == 0)
        terms[row] = m + __logf(s) - logits[(size_t)row * TCLS + y[row]];
}

// ---------------- kernel 5: mean of terms -> d_out[0] ----------------
__global__ __launch_bounds__(256) void reduce_loss_kernel(const float* __restrict__ terms,
                                                          float* __restrict__ out) {
    float s = 0.f;
    for (int i = threadIdx.x; i < BATCH; i += 256) s += terms[i];
#pragma unroll
    for (int off = 32; off > 0; off >>= 1) s += __shfl_down(s, off, 64);
    __shared__ float sh[4];
    if ((threadIdx.x & 63) == 0) sh[threadIdx.x >> 6] = s;
    __syncthreads();
    if (threadIdx.x == 0) out[0] = (sh[0] + sh[1] + sh[2] + sh[3]) * (1.0f / BATCH);
}

extern "C" void kernel_launch(void* const* d_in, const int* in_sizes, int n_in,
                              void* d_out, int out_size, void* d_ws, size_t ws_size,
                              hipStream_t stream) {
    const float* x = (const float*)d_in[0];
    const int* y = (const int*)d_in[1];
    const float* W = (const float*)d_in[2];
    const int* anc = (const int*)d_in[3];
    const int* seg = (const int*)d_in[4];
    int nnz = in_sizes[3];

    unsigned short* xb = (unsigned short*)d_ws;                 // 4 MB
    unsigned short* awb = xb + (size_t)BATCH * HID;             // 10.35 MB
    float2* partials = (float2*)(awb + (size_t)NPAD * HID);     // 4096*79*8 = 2.59 MB
    float* terms = (float*)(partials + (size_t)BATCH * NBLK);   // 16 KB
    float* loss = (float*)d_out;
    float* logits = loss + 1;                                   // [BATCH, TCLS]

    cvt_x_kernel<<<(BATCH * HID) / (256 * 4), 256, 0, stream>>>(x, xb, BATCH * HID);
    build_aw_kernel<<<NPAD, 256, 0, stream>>>(W, anc, seg, nnz, awb);
    dim3 grid(NPAD / BN, BATCH / BM);
    gemm_fused_kernel<<<grid, 256, 0, stream>>>(xb, awb, logits, partials);
    lse_kernel<<<BATCH / 4, 256, 0, stream>>>(partials, logits, y, terms);
    reduce_loss_kernel<<<1, 256, 0, stream>>>(terms, loss);
}

// Round 4
// 309.909 us; speedup vs baseline: 1.0979x; 1.0833x over previous
//
#include <hip/hip_runtime.h>
#include <hip/hip_bf16.h>

// CoverTreeLoss: aw[j] = W[j] + sum(W[ancestors(j)]); logits = x @ aw^T;
// loss = mean(logsumexp(logits[b]) - logits[b, y[b]]).
// B=4096, H=512, T=10000 (pad to 10112 = 79*128), C=16384.
// R4: (1) CSR bounds precompute kills build_aw's per-thread binary searches
//     (2) XCD-aware block swizzle for A-tile L2 residency
//     (3) aligned float4 C-stores (cols == 3 mod 4 are 16B-aligned off d_out+1)

typedef __bf16 bf16x8 __attribute__((ext_vector_type(8)));
typedef float f32x4 __attribute__((ext_vector_type(4)));
typedef unsigned short u16x8 __attribute__((ext_vector_type(8)));

#define BATCH 4096
#define HID 512
#define TCLS 10000
#define NPAD 10112   // 79 * 128
#define NBLK 79      // col-blocks = partials per row

__device__ __forceinline__ unsigned short f2bf(float f) {
    unsigned u = __float_as_uint(f);
    unsigned r = (u + 0x7fffu + ((u >> 16) & 1u)) >> 16;  // RNE, finite inputs only
    return (unsigned short)r;
}

// ---------------- kernel 1: x fp32 -> bf16 ----------------
__global__ __launch_bounds__(256) void cvt_x_kernel(const float* __restrict__ x,
                                                    unsigned short* __restrict__ xb, int n) {
    int i = (blockIdx.x * 256 + threadIdx.x) * 4;
    if (i < n) {
        float4 v = *(const float4*)(x + i);
        ushort4 o;
        o.x = f2bf(v.x); o.y = f2bf(v.y); o.z = f2bf(v.z); o.w = f2bf(v.w);
        *(ushort4*)(xb + i) = o;
    }
}

// ---------------- kernel 1b: CSR bounds from sorted segment_id ----------------
__global__ __launch_bounds__(256) void bounds_kernel(const int* __restrict__ seg, int nnz,
                                                     int* __restrict__ start,
                                                     int* __restrict__ end) {
    int i = blockIdx.x * 256 + threadIdx.x;
    if (i >= nnz) return;
    int s = seg[i];
    if (i == 0 || seg[i - 1] != s) start[s] = i;
    if (i == nnz - 1 || seg[i + 1] != s) end[s] = i + 1;
}

// ---------------- kernel 2: added_weights (bf16, zero-padded rows) ----------------
// 2 classes per 256-thread block; float4 row sum; no searches.
__global__ __launch_bounds__(256) void build_aw_kernel(const float* __restrict__ W,
                                                       const int* __restrict__ anc,
                                                       const int* __restrict__ start,
                                                       const int* __restrict__ end,
                                                       unsigned short* __restrict__ awb) {
    int j = blockIdx.x * 2 + (threadIdx.x >> 7);
    int h = (threadIdx.x & 127) * 4;
    unsigned short* dst = awb + (size_t)j * HID + h;
    if (j >= TCLS) {  // padding rows must be zero (GEMM has no guards)
        *(ushort4*)dst = make_ushort4(0, 0, 0, 0);
        return;
    }
    float4 a = *(const float4*)(W + (size_t)j * HID + h);
    int st = start[j], en = end[j];
    for (int k = st; k < en; k++) {
        float4 w = *(const float4*)(W + (size_t)anc[k] * HID + h);
        a.x += w.x; a.y += w.y; a.z += w.z; a.w += w.w;
    }
    ushort4 o;
    o.x = f2bf(a.x); o.y = f2bf(a.y); o.z = f2bf(a.z); o.w = f2bf(a.w);
    *(ushort4*)dst = o;
}

// ---------------- kernel 3: GEMM + fused softmax partials ----------------
#define BM 128
#define BN 128
#define BK 32
__global__ __launch_bounds__(256) void gemm_fused_kernel(const unsigned short* __restrict__ A,
                                                         const unsigned short* __restrict__ B,
                                                         float* __restrict__ C,
                                                         float2* __restrict__ partials) {
    __shared__ __align__(16) unsigned char smem[32 * 132 * 4];
    unsigned short* lds_a = (unsigned short*)smem;
    unsigned short* lds_b = ((unsigned short*)smem) + BM * BK;
    float* ldsc = (float*)smem;
    float2* pm = (float2*)smem;

    // XCD swizzle: 2528 blocks; xcd = cid&7, per XCD rows {xcd, xcd+8, xcd+16,
    // xcd+24} x 79 cols, row-fastest. 4 A-tiles (512KB) stay hot in 4MB L2.
    const int cid = blockIdx.x;
    const int xcd = cid & 7;
    const int lid = cid >> 3;
    const int bm = (xcd + 8 * (lid & 3)) * BM;
    const int cb = lid >> 2;
    const int bn = cb * BN;

    const int tid = threadIdx.x;
    const int wave = tid >> 6;
    const int lane = tid & 63;
    const int l15 = lane & 15;
    const int quad = lane >> 4;
    const int wm = (wave >> 1) * 64;
    const int wn = (wave & 1) * 64;

    f32x4 acc[4][4];
#pragma unroll
    for (int i = 0; i < 4; i++)
#pragma unroll
        for (int j = 0; j < 4; j++) acc[i][j] = (f32x4)0.f;

    const int c0 = tid, c1 = tid + 256;
    const unsigned short* a_g0 = A + (size_t)(bm + (c0 >> 2)) * HID + (c0 & 3) * 8;
    const unsigned short* a_g1 = A + (size_t)(bm + (c1 >> 2)) * HID + (c1 & 3) * 8;
    const unsigned short* b_g0 = B + (size_t)(bn + (c0 >> 2)) * HID + (c0 & 3) * 8;
    const unsigned short* b_g1 = B + (size_t)(bn + (c1 >> 2)) * HID + (c1 & 3) * 8;
    unsigned short* a_l0 = &lds_a[c0 * 8];
    unsigned short* a_l1 = &lds_a[c1 * 8];
    unsigned short* b_l0 = &lds_b[c0 * 8];
    unsigned short* b_l1 = &lds_b[c1 * 8];

    u16x8 ra0 = *(const u16x8*)a_g0;
    u16x8 ra1 = *(const u16x8*)a_g1;
    u16x8 rb0 = *(const u16x8*)b_g0;
    u16x8 rb1 = *(const u16x8*)b_g1;

    for (int k0 = 0; k0 < HID; k0 += BK) {
        *(u16x8*)a_l0 = ra0;
        *(u16x8*)a_l1 = ra1;
        *(u16x8*)b_l0 = rb0;
        *(u16x8*)b_l1 = rb1;
        __syncthreads();

        int kn = k0 + BK;
        if (kn < HID) {  // register prefetch of next tile overlaps MFMA
            ra0 = *(const u16x8*)(a_g0 + kn);
            ra1 = *(const u16x8*)(a_g1 + kn);
            rb0 = *(const u16x8*)(b_g0 + kn);
            rb1 = *(const u16x8*)(b_g1 + kn);
        }

        bf16x8 af[4], bfr[4];
#pragma unroll
        for (int mt = 0; mt < 4; mt++)
            af[mt] = *(const bf16x8*)&lds_a[(wm + mt * 16 + l15) * BK + quad * 8];
#pragma unroll
        for (int nt = 0; nt < 4; nt++)
            bfr[nt] = *(const bf16x8*)&lds_b[(wn + nt * 16 + l15) * BK + quad * 8];
#pragma unroll
        for (int mt = 0; mt < 4; mt++)
#pragma unroll
            for (int nt = 0; nt < 4; nt++)
                acc[mt][nt] = __builtin_amdgcn_mfma_f32_16x16x32_bf16(af[mt], bfr[nt],
                                                                      acc[mt][nt], 0, 0, 0);
        __syncthreads();
    }

    // ---- fused softmax partials (per 128-col block, per row) ----
    const int colbase = bn + wn + l15;
#pragma unroll
    for (int mt = 0; mt < 4; mt++) {
#pragma unroll
        for (int r = 0; r < 4; r++) {
            float v[4];
#pragma unroll
            for (int nt = 0; nt < 4; nt++)
                v[nt] = (colbase + nt * 16 < TCLS) ? acc[mt][nt][r] : -1e30f;
            float m = fmaxf(fmaxf(v[0], v[1]), fmaxf(v[2], v[3]));
#pragma unroll
            for (int off = 1; off < 16; off <<= 1)
                m = fmaxf(m, __shfl_xor(m, off, 64));
            float s = __expf(v[0] - m) + __expf(v[1] - m) +
                      __expf(v[2] - m) + __expf(v[3] - m);
#pragma unroll
            for (int off = 1; off < 16; off <<= 1)
                s += __shfl_xor(s, off, 64);
            if (l15 == 0) {
                int rowl = wm + mt * 16 + quad * 4 + r;
                pm[rowl * 2 + (wave & 1)] = make_float2(m, s);
            }
        }
    }
    __syncthreads();
    if (tid < 128) {
        float2 p0 = pm[tid * 2 + 0];
        float2 p1 = pm[tid * 2 + 1];
        float nm = fmaxf(p0.x, p1.x);
        float s = p0.y * __expf(p0.x - nm) + p1.y * __expf(p1.x - nm);
        partials[(size_t)(bm + tid) * NBLK + cb] = make_float2(nm, s);
    }
    __syncthreads();

    // ---- C write via LDS transpose; logits base is d_out+1 (byte offset 4),
    // so global cols == 3 mod 4 are 16B-aligned -> float4 for 124/128 cols.
#pragma unroll
    for (int t = 0; t < 4; t++) {
        if ((wave >> 1) == (t >> 1)) {
            int mtbase = (t & 1) * 2;
#pragma unroll
            for (int mi = 0; mi < 2; mi++) {
                int mt = mtbase + mi;
                int rowl = mi * 16 + quad * 4;
#pragma unroll
                for (int nt = 0; nt < 4; nt++)
#pragma unroll
                    for (int r = 0; r < 4; r++)
                        ldsc[(rowl + r) * 132 + wn + nt * 16 + l15] = acc[mt][nt][r];
            }
        }
        __syncthreads();
#pragma unroll
        for (int i = 0; i < 4; i++) {
            int idx = i * 256 + tid;          // 0..1023 = 32 rows x 32 units
            int rowl = idx >> 5;
            int q = idx & 31;
            float* rowp = C + (size_t)(bm + t * 32 + rowl) * TCLS + bn;
            const float* lrow = ldsc + rowl * 132;
            if (q < 31) {
                int colL = 3 + q * 4;
                if (bn + colL + 3 < TCLS) {
                    float4 v = make_float4(lrow[colL], lrow[colL + 1],
                                           lrow[colL + 2], lrow[colL + 3]);
                    *(float4*)(rowp + colL) = v;
                } else {
#pragma unroll
                    for (int e = 0; e < 4; e++)
                        if (bn + colL + e < TCLS) rowp[colL + e] = lrow[colL + e];
                }
            } else {
                const int cl[4] = {0, 1, 2, 127};
#pragma unroll
                for (int e = 0; e < 4; e++)
                    if (bn + cl[e] < TCLS) rowp[cl[e]] = lrow[cl[e]];
            }
        }
        __syncthreads();
    }
}

// ---------------- kernel 4: lse from partials + gather -> loss terms ----------------
__global__ __launch_bounds__(256) void lse_kernel(const float2* __restrict__ partials,
                                                  const float* __restrict__ logits,
                                                  const int* __restrict__ y,
                                                  float* __restrict__ terms) {
    int row = blockIdx.x * 4 + (threadIdx.x >> 6);
    int lane = threadIdx.x & 63;
    float m = -1e30f, s = 0.f;
    if (lane < NBLK) {
        float2 p = partials[(size_t)row * NBLK + lane];
        m = p.x; s = p.y;
    }
    if (lane + 64 < NBLK) {
        float2 p = partials[(size_t)row * NBLK + lane + 64];
        float nm = fmaxf(m, p.x);
        s = s * __expf(m - nm) + p.y * __expf(p.x - nm);
        m = nm;
    }
#pragma unroll
    for (int off = 1; off < 64; off <<= 1) {
        float om = __shfl_xor(m, off, 64);
        float os = __shfl_xor(s, off, 64);
        float nm = fmaxf(m, om);
        s = s * __expf(m - nm) + os * __expf(om - nm);
        m = nm;
    }
    if (lane == 0)
        terms[row] = m + __logf(s) - logits[(size_t)row * TCLS + y[row]];
}

// ---------------- kernel 5: mean of terms -> d_out[0] ----------------
__global__ __launch_bounds__(256) void reduce_loss_kernel(const float* __restrict__ terms,
                                                          float* __restrict__ out) {
    float s = 0.f;
    for (int i = threadIdx.x; i < BATCH; i += 256) s += terms[i];
#pragma unroll
    for (int off = 32; off > 0; off >>= 1) s += __shfl_down(s, off, 64);
    __shared__ float sh[4];
    if ((threadIdx.x & 63) == 0) sh[threadIdx.x >> 6] = s;
    __syncthreads();
    if (threadIdx.x == 0) out[0] = (sh[0] + sh[1] + sh[2] + sh[3]) * (1.0f / BATCH);
}

extern "C" void kernel_launch(void* const* d_in, const int* in_sizes, int n_in,
                              void* d_out, int out_size, void* d_ws, size_t ws_size,
                              hipStream_t stream) {
    const float* x = (const float*)d_in[0];
    const int* y = (const int*)d_in[1];
    const float* W = (const float*)d_in[2];
    const int* anc = (const int*)d_in[3];
    const int* seg = (const int*)d_in[4];
    int nnz = in_sizes[3];

    unsigned short* xb = (unsigned short*)d_ws;                 // 4 MB
    unsigned short* awb = xb + (size_t)BATCH * HID;             // 10.35 MB
    float2* partials = (float2*)(awb + (size_t)NPAD * HID);     // 2.59 MB
    float* terms = (float*)(partials + (size_t)BATCH * NBLK);   // 16 KB
    int* start = (int*)(terms + BATCH);                         // 40 KB
    int* end = start + TCLS;                                    // 40 KB
    float* loss = (float*)d_out;
    float* logits = loss + 1;                                   // [BATCH, TCLS]

    cvt_x_kernel<<<(BATCH * HID) / (256 * 4), 256, 0, stream>>>(x, xb, BATCH * HID);
    bounds_kernel<<<(nnz + 255) / 256, 256, 0, stream>>>(seg, nnz, start, end);
    build_aw_kernel<<<NPAD / 2, 256, 0, stream>>>(W, anc, start, end, awb);
    gemm_fused_kernel<<<(NPAD / BN) * (BATCH / BM), 256, 0, stream>>>(xb, awb, logits, partials);
    lse_kernel<<<BATCH / 4, 256, 0, stream>>>(partials, logits, y, terms);
    reduce_loss_kernel<<<1, 256, 0, stream>>>(terms, loss);
}